// Round 1
// baseline (7085.571 us; speedup 1.0000x reference)
//
#include <hip/hip_runtime.h>
#include <cmath>

#define ROWS 8
#define THREADS 512
#define NB 2048
#define TSTEPS 128
#define DXF 409

struct Params {
  const float *x;
  const float *Wl,*bWl,*Ul,*bUl,*Vl,*bVl;
  const float *Wa,*bWa,*Ua,*bUa,*Va,*bVa;
  const float *Wv,*bWv,*Uv,*bUv,*Vv,*bVv;
  const float *nlW1,*nlb1,*nlW2,*nlb2;
  const float *naW1,*nab1,*naW2,*nab2;
  const float *nvW1,*nvb1,*nvW2,*nvb2;
  const float *attW1,*attb1,*attW2,*attb2;
  const float *outW1,*outb1,*outW2,*outb2;
  float *out;
};

__device__ __forceinline__ float sigm(float x){ return 1.0f/(1.0f+__expf(-x)); }

// Accumulate in[r][0:KDIM] @ W[0:KDIM][COLS] into acc[r] at column j.
// Weights: coalesced global loads (lane = j). Activations: LDS broadcast float4.
template<int COLS,int KDIM,int INSTRIDE>
__device__ __forceinline__ void acc_mm(const float* __restrict__ W,
                                       const float* __restrict__ in,
                                       float acc[ROWS], int j)
{
  constexpr int K4 = KDIM/4;
  #pragma unroll 2
  for (int k4=0;k4<K4;k4++){
    const int k=4*k4;
    float w0=W[(k+0)*COLS+j];
    float w1=W[(k+1)*COLS+j];
    float w2=W[(k+2)*COLS+j];
    float w3=W[(k+3)*COLS+j];
    #pragma unroll
    for (int r=0;r<ROWS;r++){
      const float4 v = *(const float4*)(in + r*INSTRIDE + k);
      acc[r]=fmaf(v.w,w3,fmaf(v.z,w2,fmaf(v.y,w1,fmaf(v.x,w0,acc[r]))));
    }
  }
  if constexpr ((KDIM & 3) != 0) {
    #pragma unroll
    for (int k=K4*4;k<KDIM;k++){
      float wv=W[k*COLS+j];
      #pragma unroll
      for (int r=0;r<ROWS;r++) acc[r]=fmaf(in[r*INSTRIDE+k],wv,acc[r]);
    }
  }
}

__global__ __launch_bounds__(THREADS)
void tman_kernel(Params p)
{
  // x staged per step (segments padded so row stride is 16B-aligned)
  __shared__ float xsl[ROWS][300];
  __shared__ float xsa[ROWS][76];   // 74 used
  __shared__ float xsv[ROWS][36];   // 35 used
  // recurrent state
  __shared__ float cl[ROWS][128], hl[ROWS][128];
  __shared__ float ca[ROWS][64],  ha[ROWS][64];
  __shared__ float cv[ROWS][64],  hv[ROWS][64];
  __shared__ float zz[ROWS][64];
  // gate pre-activations
  __shared__ float sl[ROWS][512];
  __shared__ float sa[ROWS][256];
  __shared__ float sv[ROWS][256];
  // MLP intermediates
  __shared__ float hidl[ROWS][128], hida[ROWS][128], hidv[ROWS][128], hidat[ROWS][128];
  __shared__ float scl[ROWS][64], sca[ROWS][64], scv[ROWS][64];
  __shared__ float attlog[ROWS][4];
  // combined gate biases
  __shared__ float bl[512], ba[256], bv[256];

  const int tid  = threadIdx.x;
  const int lane = tid & 63;
  const int wave = tid >> 6;
  const int n0   = blockIdx.x * ROWS;

  // --- init: biases + zero state ---
  for (int i=tid;i<512;i+=THREADS) bl[i]=p.bWl[i]+p.bUl[i]+p.bVl[i];
  for (int i=tid;i<256;i+=THREADS){ ba[i]=p.bWa[i]+p.bUa[i]+p.bVa[i]; bv[i]=p.bWv[i]+p.bUv[i]+p.bVv[i]; }
  for (int i=tid;i<ROWS*128;i+=THREADS){ (&cl[0][0])[i]=0.f; (&hl[0][0])[i]=0.f; }
  for (int i=tid;i<ROWS*64;i+=THREADS){
    (&ca[0][0])[i]=0.f; (&ha[0][0])[i]=0.f;
    (&cv[0][0])[i]=0.f; (&hv[0][0])[i]=0.f;
    (&zz[0][0])[i]=0.f;
  }
  __syncthreads();

  for (int t=0;t<TSTEPS;++t){
    // ---- A: stage x[t] rows ----
    const float* xt = p.x + ((size_t)t*NB + n0)*DXF;
    for (int i=tid;i<ROWS*DXF;i+=THREADS){
      int r=i/DXF, d=i-r*DXF;
      float v=xt[(size_t)r*DXF+d];
      if (d<300) xsl[r][d]=v;
      else if (d<374) xsa[r][d-300]=v;
      else xsv[r][d-374]=v;
    }
    __syncthreads();

    // ---- B: gate pre-activations s = xW + hU + zV + b ----
    { // every wave: one 64-col block of L (8 blocks of 512)
      int j = wave*64 + lane;
      float acc[ROWS]; float b=bl[j];
      #pragma unroll
      for (int r=0;r<ROWS;r++) acc[r]=b;
      acc_mm<512,300,300>(p.Wl,&xsl[0][0],acc,j);
      acc_mm<512,128,128>(p.Ul,&hl[0][0],acc,j);
      acc_mm<512, 64, 64>(p.Vl,&zz[0][0],acc,j);
      #pragma unroll
      for (int r=0;r<ROWS;r++) sl[r][j]=acc[r];
    }
    { // second item: waves 0-3 -> V blocks 3..0, waves 4-7 -> A blocks 3..0
      int item = 15-wave;
      if (item>=12){
        int j=(item-12)*64+lane;
        float acc[ROWS]; float b=bv[j];
        #pragma unroll
        for (int r=0;r<ROWS;r++) acc[r]=b;
        acc_mm<256,35,36>(p.Wv,&xsv[0][0],acc,j);
        acc_mm<256,64,64>(p.Uv,&hv[0][0],acc,j);
        acc_mm<256,64,64>(p.Vv,&zz[0][0],acc,j);
        #pragma unroll
        for (int r=0;r<ROWS;r++) sv[r][j]=acc[r];
      } else {
        int j=(item-8)*64+lane;
        float acc[ROWS]; float b=ba[j];
        #pragma unroll
        for (int r=0;r<ROWS;r++) acc[r]=b;
        acc_mm<256,74,76>(p.Wa,&xsa[0][0],acc,j);
        acc_mm<256,64,64>(p.Ua,&ha[0][0],acc,j);
        acc_mm<256,64,64>(p.Va,&zz[0][0],acc,j);
        #pragma unroll
        for (int r=0;r<ROWS;r++) sa[r][j]=acc[r];
      }
    }
    __syncthreads();

    // ---- C: gates -> new c,h ----
    for (int i=tid;i<ROWS*128;i+=THREADS){
      int r=i>>7, u=i&127;
      float f =sigm(sl[r][u]);
      float ig=sigm(sl[r][128+u]);
      float o =sigm(sl[r][256+u]);
      float ch=tanhf(sl[r][384+u]);
      float c=f*cl[r][u]+ig*ch;
      cl[r][u]=c; hl[r][u]=tanhf(c)*o;
    }
    for (int i=tid;i<ROWS*64;i+=THREADS){
      int r=i>>6, u=i&63;
      { float f=sigm(sa[r][u]), ig=sigm(sa[r][64+u]), o=sigm(sa[r][128+u]), ch=tanhf(sa[r][192+u]);
        float c=f*ca[r][u]+ig*ch; ca[r][u]=c; ha[r][u]=tanhf(c)*o; }
      { float f=sigm(sv[r][u]), ig=sigm(sv[r][64+u]), o=sigm(sv[r][128+u]), ch=tanhf(sv[r][192+u]);
        float c=f*cv[r][u]+ig*ch; cv[r][u]=c; hv[r][u]=tanhf(c)*o; }
    }
    __syncthreads();

    // ---- D1: hidden layers of the 3 score-MLPs (input = NEW cell states) + att MLP ----
    if (wave<2){
      int j=wave*64+lane;
      float acc[ROWS]; float b=p.nlb1[j];
      #pragma unroll
      for (int r=0;r<ROWS;r++) acc[r]=b;
      acc_mm<128,128,128>(p.nlW1,&cl[0][0],acc,j);
      #pragma unroll
      for (int r=0;r<ROWS;r++) hidl[r][j]=fmaxf(acc[r],0.f);
    } else if (wave<4){
      int j=(wave-2)*64+lane;
      float acc[ROWS]; float b=p.nab1[j];
      #pragma unroll
      for (int r=0;r<ROWS;r++) acc[r]=b;
      acc_mm<128,64,64>(p.naW1,&ca[0][0],acc,j);
      #pragma unroll
      for (int r=0;r<ROWS;r++) hida[r][j]=fmaxf(acc[r],0.f);
    } else if (wave<6){
      int j=(wave-4)*64+lane;
      float acc[ROWS]; float b=p.nvb1[j];
      #pragma unroll
      for (int r=0;r<ROWS;r++) acc[r]=b;
      acc_mm<128,64,64>(p.nvW1,&cv[0][0],acc,j);
      #pragma unroll
      for (int r=0;r<ROWS;r++) hidv[r][j]=fmaxf(acc[r],0.f);
    } else {
      int j=(wave-6)*64+lane;
      float acc[ROWS]; float b=p.attb1[j];
      #pragma unroll
      for (int r=0;r<ROWS;r++) acc[r]=b;
      acc_mm<128,128,128>(p.attW1,          &cl[0][0],acc,j);
      acc_mm<128, 64, 64>(p.attW1+128*128,  &ca[0][0],acc,j);
      acc_mm<128, 64, 64>(p.attW1+192*128,  &cv[0][0],acc,j);
      #pragma unroll
      for (int r=0;r<ROWS;r++) hidat[r][j]=fmaxf(acc[r],0.f);
    }
    __syncthreads();

    // ---- D2: second layers ----
    if (wave==0){
      float acc[ROWS]; float b=p.nlb2[lane];
      #pragma unroll
      for (int r=0;r<ROWS;r++) acc[r]=b;
      acc_mm<64,128,128>(p.nlW2,&hidl[0][0],acc,lane);
      #pragma unroll
      for (int r=0;r<ROWS;r++) scl[r][lane]=acc[r];
    } else if (wave==1){
      float acc[ROWS]; float b=p.nab2[lane];
      #pragma unroll
      for (int r=0;r<ROWS;r++) acc[r]=b;
      acc_mm<64,128,128>(p.naW2,&hida[0][0],acc,lane);
      #pragma unroll
      for (int r=0;r<ROWS;r++) sca[r][lane]=acc[r];
    } else if (wave==2){
      float acc[ROWS]; float b=p.nvb2[lane];
      #pragma unroll
      for (int r=0;r<ROWS;r++) acc[r]=b;
      acc_mm<64,128,128>(p.nvW2,&hidv[0][0],acc,lane);
      #pragma unroll
      for (int r=0;r<ROWS;r++) scv[r][lane]=acc[r];
    } else if (wave==3 && lane<ROWS*3){
      int r=lane/3, m=lane-3*r;
      float a=p.attb2[m];
      for (int k=0;k<128;k++) a=fmaf(hidat[r][k],p.attW2[k*3+m],a);
      attlog[r][m]=a;
    }
    __syncthreads();

    // ---- D3: softmax over 3 modalities + z update ----
    for (int i=tid;i<ROWS*64;i+=THREADS){
      int r=i>>6, u=i&63;
      float a0=attlog[r][0], a1=attlog[r][1], a2=attlog[r][2];
      float m=fmaxf(a0,fmaxf(a1,a2));
      float e0=__expf(a0-m), e1=__expf(a1-m), e2=__expf(a2-m);
      float inv=1.f/(e0+e1+e2);
      zz[r][u]=(e0*scl[r][u]+e1*sca[r][u]+e2*scv[r][u])*inv;
    }
    __syncthreads();
  }

  // ---- E: final MLP  last=[hl,ha,hv,z] (320) -> 128 relu -> 1 ----
  if (wave<2){
    int j=wave*64+lane;
    float acc[ROWS]; float b=p.outb1[j];
    #pragma unroll
    for (int r=0;r<ROWS;r++) acc[r]=b;
    acc_mm<128,128,128>(p.outW1,          &hl[0][0],acc,j);
    acc_mm<128, 64, 64>(p.outW1+128*128,  &ha[0][0],acc,j);
    acc_mm<128, 64, 64>(p.outW1+192*128,  &hv[0][0],acc,j);
    acc_mm<128, 64, 64>(p.outW1+256*128,  &zz[0][0],acc,j);
    #pragma unroll
    for (int r=0;r<ROWS;r++) hidl[r][j]=fmaxf(acc[r],0.f);
  }
  __syncthreads();
  if (tid<ROWS){
    float acc=p.outb2[0];
    for (int k=0;k<128;k++) acc=fmaf(hidl[tid][k],p.outW2[k],acc);
    p.out[n0+tid]=acc;
  }
}

extern "C" void kernel_launch(void* const* d_in, const int* in_sizes, int n_in,
                              void* d_out, int out_size, void* d_ws, size_t ws_size,
                              hipStream_t stream) {
  const float* const* f = (const float* const*)d_in;
  Params P;
  P.x  =f[0];
  P.Wl =f[1];  P.bWl=f[2];  P.Ul =f[3];  P.bUl=f[4];  P.Vl =f[5];  P.bVl=f[6];
  P.Wa =f[7];  P.bWa=f[8];  P.Ua =f[9];  P.bUa=f[10]; P.Va =f[11]; P.bVa=f[12];
  P.Wv =f[13]; P.bWv=f[14]; P.Uv =f[15]; P.bUv=f[16]; P.Vv =f[17]; P.bVv=f[18];
  P.nlW1=f[19]; P.nlb1=f[20]; P.nlW2=f[21]; P.nlb2=f[22];
  P.naW1=f[23]; P.nab1=f[24]; P.naW2=f[25]; P.nab2=f[26];
  P.nvW1=f[27]; P.nvb1=f[28]; P.nvW2=f[29]; P.nvb2=f[30];
  P.attW1=f[31]; P.attb1=f[32]; P.attW2=f[33]; P.attb2=f[34];
  P.outW1=f[35]; P.outb1=f[36]; P.outW2=f[37]; P.outb2=f[38];
  P.out=(float*)d_out;
  hipLaunchKernelGGL(tman_kernel, dim3(NB/ROWS), dim3(THREADS), 0, stream, P);
}